// Round 20
// baseline (307.789 us; speedup 1.0000x reference)
//
#include <hip/hip_runtime.h>
#include <hip/hip_bf16.h>
#include <stdint.h>

#define B_   4
#define S_   2048
#define H_   16
#define HD_  64
#define D_   1024

typedef short  short8  __attribute__((ext_vector_type(8)));
typedef float  f32x4   __attribute__((ext_vector_type(4)));
typedef float  f32x16  __attribute__((ext_vector_type(16)));

__device__ __forceinline__ unsigned short f2bf(float f) {
    union { float f; unsigned u; } v; v.f = f;
    unsigned r = v.u + 0x7fffu + ((v.u >> 16) & 1u);
    return (unsigned short)(r >> 16);
}

#if __has_builtin(__builtin_amdgcn_exp2f)
#define EXP2(x) __builtin_amdgcn_exp2f(x)
#else
#define EXP2(x) exp2f(x)
#endif

__device__ __forceinline__ unsigned cvtpk(float lo, float hi) {
    unsigned r;
    asm("v_cvt_pk_bf16_f32 %0, %1, %2" : "=v"(r) : "v"(lo), "v"(hi));
    return r;
}

__device__ __forceinline__ float bq(float v, int srclane) {
    return __int_as_float(__builtin_amdgcn_ds_bpermute(srclane << 2, __float_as_int(v)));
}

// v_permlane32_swap_b32: x' = [x.lo | y.lo], y' = [x.hi | y.hi]
__device__ __forceinline__ void pl32swap(unsigned &x, unsigned &y) {
    asm volatile("v_permlane32_swap_b32 %0, %1" : "+v"(x), "+v"(y));
}

#define MFMA32(a, b, c) __builtin_amdgcn_mfma_f32_32x32x16_bf16(a, b, c, 0, 0, 0)
#define MFMA16(a, b, c) __builtin_amdgcn_mfma_f32_16x16x32_bf16(a, b, c, 0, 0, 0)

// ---------------- fp32 -> bf16 convert (vectorized) ----------------
__global__ __launch_bounds__(256) void k_cvt(const float* __restrict__ in,
                                             unsigned short* __restrict__ out) {
    int i = (blockIdx.x * 256 + threadIdx.x) * 4;
    float4 f = *(const float4*)(in + i);
    ushort4 o;
    o.x = f2bf(f.x); o.y = f2bf(f.y); o.z = f2bf(f.z); o.w = f2bf(f.w);
    *(ushort4*)(out + i) = o;
}

// ---------- transpose + convert: in[K][N] f32 -> out[N][K] bf16 ----------
__global__ __launch_bounds__(256) void k_transpose_cvt(const float* __restrict__ in,
                                                       unsigned short* __restrict__ out,
                                                       int K, int N) {
    __shared__ float tile[32][33];
    int n0 = blockIdx.x * 32, k0 = blockIdx.y * 32;
    int tx = threadIdx.x, ty = threadIdx.y;
#pragma unroll
    for (int i = 0; i < 32; i += 8)
        tile[ty + i][tx] = in[(size_t)(k0 + ty + i) * N + n0 + tx];
    __syncthreads();
#pragma unroll
    for (int i = 0; i < 32; i += 8)
        out[(size_t)(n0 + ty + i) * K + k0 + tx] = f2bf(tile[tx][ty + i]);
}

__device__ __forceinline__ void async_load16(const unsigned short* g, unsigned short* l) {
    __builtin_amdgcn_global_load_lds(
        (const __attribute__((address_space(1))) unsigned int*)g,
        (__attribute__((address_space(3))) unsigned int*)l, 16, 0, 0);
}

// ============ balanced 8-wave 256x128 GEMM (QKV projection) ============
// (r19-proven, unchanged) Triple-buffered LDS, 2 phases/K-tile, vmcnt(6).
template <int TPOSED>
__global__ __launch_bounds__(512, 1) void k_gemm8(const unsigned short* __restrict__ A,
                                                  const unsigned short* __restrict__ BT,
                                                  const float* __restrict__ bias,
                                                  unsigned short* __restrict__ qb,
                                                  unsigned short* __restrict__ kb,
                                                  unsigned short* __restrict__ vtb,
                                                  int M, int N, int K, int nbase) {
    __shared__ __attribute__((aligned(16))) unsigned short A0s[256 * 64];
    __shared__ __attribute__((aligned(16))) unsigned short A1s[256 * 64];
    __shared__ __attribute__((aligned(16))) unsigned short A2s[256 * 64];
    __shared__ __attribute__((aligned(16))) unsigned short W0s[128 * 64];
    __shared__ __attribute__((aligned(16))) unsigned short W1s[128 * 64];
    __shared__ __attribute__((aligned(16))) unsigned short W2s[128 * 64];
    const int tid = threadIdx.x, wave = tid >> 6, lane = tid & 63;
    const int wR = wave >> 2, wC = wave & 3;
    const int m0 = blockIdx.y * 256, n0 = nbase + blockIdx.x * 128;

    const unsigned short* AG = A + (size_t)m0 * K;
    const unsigned short* WG = BT + (size_t)n0 * K;

    const int rbase = wave * 8 + (lane >> 3);
    const int scol8 = ((lane & 7) ^ ((lane >> 3) & 7)) * 8;
    const int sdst  = wave * 512;
    const int q15 = lane & 15, q4 = (lane >> 4) << 2;
    const int cb0 = ((lane >> 4) * 16) ^ ((lane & 7) << 4);
    const int cb1 = (64 + (lane >> 4) * 16) ^ ((lane & 7) << 4);

    f32x4 acc[2][4][2] = {};

#define STAGE3(SA, SW, KT, KH)                                                        \
    if ((KH) == 0) {                                                                  \
        async_load16(AG + (size_t)(rbase)       * K + (KT) + scol8, (SA) + 0 * 4096 + sdst); \
        async_load16(AG + (size_t)(64 + rbase)  * K + (KT) + scol8, (SA) + 1 * 4096 + sdst); \
        async_load16(WG + (size_t)(rbase)       * K + (KT) + scol8, (SW) + 0 * 4096 + sdst); \
    } else {                                                                          \
        async_load16(AG + (size_t)(128 + rbase) * K + (KT) + scol8, (SA) + 2 * 4096 + sdst); \
        async_load16(AG + (size_t)(192 + rbase) * K + (KT) + scol8, (SA) + 3 * 4096 + sdst); \
        async_load16(WG + (size_t)(64 + rbase)  * K + (KT) + scol8, (SW) + 1 * 4096 + sdst); \
    }

#define PHASEBODY(CA, CW, SA, SW, MORE, KT2, KH, CB)                                  \
    {                                                                                 \
        short8 xf[2][4], yf[2][2];                                                    \
        if (TPOSED) {                                                                 \
            _Pragma("unroll")                                                         \
            for (int i = 0; i < 4; ++i)                                               \
                xf[0][i] = *(const short8*)((const char*)(CW) + (wR * 64 + i * 16 + q15) * 128 + (CB)); \
            _Pragma("unroll")                                                         \
            for (int h = 0; h < 2; ++h)                                               \
                _Pragma("unroll")                                                     \
                for (int j = 0; j < 2; ++j)                                           \
                    yf[h][j] = *(const short8*)((const char*)(CA) + (h * 128 + wC * 32 + j * 16 + q15) * 128 + (CB)); \
        } else {                                                                      \
            _Pragma("unroll")                                                         \
            for (int h = 0; h < 2; ++h)                                               \
                _Pragma("unroll")                                                     \
                for (int i = 0; i < 4; ++i)                                           \
                    xf[h][i] = *(const short8*)((const char*)(CA) + (h * 128 + wR * 64 + i * 16 + q15) * 128 + (CB)); \
            _Pragma("unroll")                                                         \
            for (int j = 0; j < 2; ++j)                                               \
                yf[0][j] = *(const short8*)((const char*)(CW) + (wC * 32 + j * 16 + q15) * 128 + (CB)); \
        }                                                                             \
        if (MORE) {                                                                   \
            STAGE3(SA, SW, KT2, KH)                                                   \
            asm volatile("s_waitcnt vmcnt(6)" ::: "memory");                          \
        } else {                                                                      \
            asm volatile("s_waitcnt vmcnt(0)" ::: "memory");                          \
        }                                                                             \
        __builtin_amdgcn_s_barrier();                                                 \
        asm volatile("s_waitcnt lgkmcnt(0)" ::: "memory");                            \
        __builtin_amdgcn_sched_barrier(0);                                            \
        __builtin_amdgcn_s_setprio(1);                                                \
        _Pragma("unroll")                                                             \
        for (int h = 0; h < 2; ++h)                                                   \
            _Pragma("unroll")                                                         \
            for (int i = 0; i < 4; ++i)                                               \
                _Pragma("unroll")                                                     \
                for (int j = 0; j < 2; ++j)                                           \
                    acc[h][i][j] = MFMA16(TPOSED ? xf[0][i] : xf[h][i],               \
                                          TPOSED ? yf[h][j] : yf[0][j],               \
                                          acc[h][i][j]);                              \
        __builtin_amdgcn_s_setprio(0);                                                \
        asm volatile("" ::: "memory");                                                \
        __builtin_amdgcn_s_barrier();                                                 \
    }

#define TILEBODY(CA, CW, SA, SW, TC)                                                  \
    {                                                                                 \
        const int more_ = ((TC) + 2) < 16;                                            \
        const int kt2_ = ((TC) + 2) * 64;                                             \
        PHASEBODY(CA, CW, SA, SW, more_, kt2_, 0, cb0)                                \
        PHASEBODY(CA, CW, SA, SW, more_, kt2_, 1, cb1)                                \
    }

    STAGE3(A0s, W0s, 0, 0)
    STAGE3(A0s, W0s, 0, 1)
    STAGE3(A1s, W1s, 64, 0)
    STAGE3(A1s, W1s, 64, 1)
    asm volatile("s_waitcnt vmcnt(6)" ::: "memory");
    __builtin_amdgcn_s_barrier();

    for (int t = 0; t < 15; t += 3) {
        TILEBODY(A0s, W0s, A2s, W2s, t)
        TILEBODY(A1s, W1s, A0s, W0s, t + 1)
        TILEBODY(A2s, W2s, A1s, W1s, t + 2)
    }
    TILEBODY(A0s, W0s, A2s, W2s, 15)
#undef STAGE3
#undef PHASEBODY
#undef TILEBODY

    if (TPOSED) {
        unsigned short* dst = (n0 < 1024) ? qb : kb;
        const float scale = (n0 < 1024) ? 0.18033688011112042f : 1.0f;
#pragma unroll
        for (int i = 0; i < 4; ++i) {
            int nr = n0 + wR * 64 + i * 16 + q4;
            float4 bv4 = *(const float4*)(bias + nr);
            int d0 = nr & 63, hh = (nr & 1023) >> 6;
#pragma unroll
            for (int h = 0; h < 2; ++h)
#pragma unroll
            for (int j = 0; j < 2; ++j) {
                int mc = m0 + h * 128 + wC * 32 + j * 16 + q15;
                int b = mc >> 11, s = mc & 2047;
                size_t bh = (size_t)(b * 16 + hh);
                f32x4 a = acc[h][i][j];
                ushort4 o;
                o.x = f2bf((a[0] + bv4.x) * scale);
                o.y = f2bf((a[1] + bv4.y) * scale);
                o.z = f2bf((a[2] + bv4.z) * scale);
                o.w = f2bf((a[3] + bv4.w) * scale);
                size_t off = bh * 131072 +
                    (size_t)((s >> 5) * 4 + (d0 >> 4)) * 512 +
                    ((s & 31) * 2 + ((d0 >> 3) & 1)) * 8 + (d0 & 7);
                *(ushort4*)(dst + off) = o;
            }
        }
    } else {
#pragma unroll
        for (int h = 0; h < 2; ++h)
#pragma unroll
        for (int i = 0; i < 4; ++i) {
            int mr = m0 + h * 128 + wR * 64 + i * 16 + q4;
            int b = mr >> 11, s0 = mr & 2047;
#pragma unroll
            for (int j = 0; j < 2; ++j) {
                int nc = n0 + wC * 32 + j * 16 + q15;
                int rem = nc & 1023, hh = rem >> 6, d = rem & 63;
                float bv = bias[nc];
                f32x4 a = acc[h][i][j];
                ushort4 o;
                o.x = f2bf(a[0] + bv);
                o.y = f2bf(a[1] + bv);
                o.z = f2bf(a[2] + bv);
                o.w = f2bf(a[3] + bv);
                size_t bh = (size_t)(b * 16 + hh);
                size_t off = bh * 131072 +
                    (size_t)((s0 >> 5) * 4 + (d >> 5) * 2 + ((s0 >> 4) & 1)) * 512 +
                    (((d & 31) << 1) + ((s0 >> 3) & 1)) * 8 + (s0 & 7);
                *(ushort4*)(vtb + off) = o;
            }
        }
    }
}

// ============ output projection: 8-phase 256x128, fp32 float4 epilogue ============
// Clone of k_gemm8 TPOSED=1 path (r19-verified); C-rows = n -> float4 stores.
// grid 8x32 = 256 blocks = exactly 1/CU.
__global__ __launch_bounds__(512, 1) void k_gemm_out8(const unsigned short* __restrict__ A,
                                                      const unsigned short* __restrict__ BT,
                                                      const float* __restrict__ bias,
                                                      float* __restrict__ outf,
                                                      int M, int N, int K) {
    __shared__ __attribute__((aligned(16))) unsigned short A0s[256 * 64];
    __shared__ __attribute__((aligned(16))) unsigned short A1s[256 * 64];
    __shared__ __attribute__((aligned(16))) unsigned short A2s[256 * 64];
    __shared__ __attribute__((aligned(16))) unsigned short W0s[128 * 64];
    __shared__ __attribute__((aligned(16))) unsigned short W1s[128 * 64];
    __shared__ __attribute__((aligned(16))) unsigned short W2s[128 * 64];
    const int tid = threadIdx.x, wave = tid >> 6, lane = tid & 63;
    const int wR = wave >> 2, wC = wave & 3;
    const int m0 = blockIdx.y * 256, n0 = blockIdx.x * 128;

    const unsigned short* AG = A + (size_t)m0 * K;
    const unsigned short* WG = BT + (size_t)n0 * K;

    const int rbase = wave * 8 + (lane >> 3);
    const int scol8 = ((lane & 7) ^ ((lane >> 3) & 7)) * 8;
    const int sdst  = wave * 512;
    const int q15 = lane & 15, q4 = (lane >> 4) << 2;
    const int cb0 = ((lane >> 4) * 16) ^ ((lane & 7) << 4);
    const int cb1 = (64 + (lane >> 4) * 16) ^ ((lane & 7) << 4);

    f32x4 acc[2][4][2] = {};

#define STAGE3O(SA, SW, KT, KH)                                                       \
    if ((KH) == 0) {                                                                  \
        async_load16(AG + (size_t)(rbase)       * K + (KT) + scol8, (SA) + 0 * 4096 + sdst); \
        async_load16(AG + (size_t)(64 + rbase)  * K + (KT) + scol8, (SA) + 1 * 4096 + sdst); \
        async_load16(WG + (size_t)(rbase)       * K + (KT) + scol8, (SW) + 0 * 4096 + sdst); \
    } else {                                                                          \
        async_load16(AG + (size_t)(128 + rbase) * K + (KT) + scol8, (SA) + 2 * 4096 + sdst); \
        async_load16(AG + (size_t)(192 + rbase) * K + (KT) + scol8, (SA) + 3 * 4096 + sdst); \
        async_load16(WG + (size_t)(64 + rbase)  * K + (KT) + scol8, (SW) + 1 * 4096 + sdst); \
    }

#define PHASEBODYO(CA, CW, SA, SW, MORE, KT2, KH, CB)                                 \
    {                                                                                 \
        short8 xf[4], yf[2][2];                                                       \
        _Pragma("unroll")                                                             \
        for (int i = 0; i < 4; ++i)                                                   \
            xf[i] = *(const short8*)((const char*)(CW) + (wR * 64 + i * 16 + q15) * 128 + (CB)); \
        _Pragma("unroll")                                                             \
        for (int h = 0; h < 2; ++h)                                                   \
            _Pragma("unroll")                                                         \
            for (int j = 0; j < 2; ++j)                                               \
                yf[h][j] = *(const short8*)((const char*)(CA) + (h * 128 + wC * 32 + j * 16 + q15) * 128 + (CB)); \
        if (MORE) {                                                                   \
            STAGE3O(SA, SW, KT2, KH)                                                  \
            asm volatile("s_waitcnt vmcnt(6)" ::: "memory");                          \
        } else {                                                                      \
            asm volatile("s_waitcnt vmcnt(0)" ::: "memory");                          \
        }                                                                             \
        __builtin_amdgcn_s_barrier();                                                 \
        asm volatile("s_waitcnt lgkmcnt(0)" ::: "memory");                            \
        __builtin_amdgcn_sched_barrier(0);                                            \
        __builtin_amdgcn_s_setprio(1);                                                \
        _Pragma("unroll")                                                             \
        for (int h = 0; h < 2; ++h)                                                   \
            _Pragma("unroll")                                                         \
            for (int i = 0; i < 4; ++i)                                               \
                _Pragma("unroll")                                                     \
                for (int j = 0; j < 2; ++j)                                           \
                    acc[h][i][j] = MFMA16(xf[i], yf[h][j], acc[h][i][j]);             \
        __builtin_amdgcn_s_setprio(0);                                                \
        asm volatile("" ::: "memory");                                                \
        __builtin_amdgcn_s_barrier();                                                 \
    }

#define TILEBODYO(CA, CW, SA, SW, TC)                                                 \
    {                                                                                 \
        const int more_ = ((TC) + 2) < 16;                                            \
        const int kt2_ = ((TC) + 2) * 64;                                             \
        PHASEBODYO(CA, CW, SA, SW, more_, kt2_, 0, cb0)                               \
        PHASEBODYO(CA, CW, SA, SW, more_, kt2_, 1, cb1)                               \
    }

    STAGE3O(A0s, W0s, 0, 0)
    STAGE3O(A0s, W0s, 0, 1)
    STAGE3O(A1s, W1s, 64, 0)
    STAGE3O(A1s, W1s, 64, 1)
    asm volatile("s_waitcnt vmcnt(6)" ::: "memory");
    __builtin_amdgcn_s_barrier();

    for (int t = 0; t < 15; t += 3) {
        TILEBODYO(A0s, W0s, A2s, W2s, t)
        TILEBODYO(A1s, W1s, A0s, W0s, t + 1)
        TILEBODYO(A2s, W2s, A1s, W1s, t + 2)
    }
    TILEBODYO(A0s, W0s, A2s, W2s, 15)
#undef STAGE3O
#undef PHASEBODYO
#undef TILEBODYO

    // epilogue: C-rows = n (quad-contiguous) -> float4 stores to out[m][n]
#pragma unroll
    for (int i = 0; i < 4; ++i) {
        int nr = n0 + wR * 64 + i * 16 + q4;
        float4 bv4 = *(const float4*)(bias + nr);
#pragma unroll
        for (int h = 0; h < 2; ++h)
#pragma unroll
        for (int j = 0; j < 2; ++j) {
            int mc = m0 + h * 128 + wC * 32 + j * 16 + q15;
            f32x4 a = acc[h][i][j];
            float4 o;
            o.x = a[0] + bv4.x;
            o.y = a[1] + bv4.y;
            o.z = a[2] + bv4.z;
            o.w = a[3] + bv4.w;
            *(float4*)(outf + (size_t)mc * N + nr) = o;
        }
    }
}

// ---- one 32-q strip: fixed-max softmax, split MFMA accumulators, permlane pack.
// All Q/K/V fragment loads are 1KB coalesced wave-loads from fragment-major buffers. ----
__device__ __forceinline__ void do_strip(int strip, int bh, int c, int hi,
                                         const unsigned short* __restrict__ QFb,
                                         const unsigned short* __restrict__ KFb,
                                         const unsigned short* __restrict__ VFb,
                                         unsigned short* __restrict__ Z) {
    const int qbase = strip * 32;
    const int b = bh >> 4, h = bh & 15;
    const int lp8 = ((c << 1) + hi) << 3;      // lane-slot offset within 512-elem block

    short8 qf[4];
#pragma unroll
    for (int kd = 0; kd < 4; kd++)
        qf[kd] = *(const short8*)(QFb + (strip * 4 + kd) * 512 + lp8);

    f32x16 o0a = {}, o0b = {}, o1a = {}, o1b = {};
    float l_r = 0.f;
    const int nkv = strip + 1;

    short8 kf_cur[4], kf_nxt[4];
#pragma unroll
    for (int kd = 0; kd < 4; kd++)
        kf_cur[kd] = *(const short8*)(KFb + kd * 512 + lp8);

    for (int tt = 0; tt < nkv; ++tt) {
        const int tn = (tt + 1 < nkv) ? (tt + 1) : tt;    // clamped prefetch
#pragma unroll
        for (int kd = 0; kd < 4; kd++)
            kf_nxt[kd] = *(const short8*)(KFb + (tn * 4 + kd) * 512 + lp8);

        short8 vf[2][2];
#pragma unroll
        for (int dt = 0; dt < 2; dt++)
#pragma unroll
            for (int ks = 0; ks < 2; ks++)
                vf[dt][ks] = *(const short8*)(VFb + (tt * 4 + dt * 2 + ks) * 512 + lp8);

        // QK^T: two independent 2-chains
        f32x16 sTa = {}, sTb = {};
        sTa = MFMA32(kf_cur[0], qf[0], sTa);
        sTb = MFMA32(kf_cur[2], qf[2], sTb);
        sTa = MFMA32(kf_cur[1], qf[1], sTa);
        sTb = MFMA32(kf_cur[3], qf[3], sTb);
        f32x16 sT;
#pragma unroll
        for (int r = 0; r < 16; r++) sT[r] = sTa[r] + sTb[r];

        if (tt * 32 == qbase) {          // diagonal tile: mask t_local > q_local
#pragma unroll
            for (int r = 0; r < 16; r++) {
                int tl = (r & 3) + 8 * (r >> 2) + 4 * hi;
                if (tl > c) sT[r] = -1e30f;
            }
        }

        // fixed-max softmax: P = exp2(s) directly (logits bounded, f32-safe)
#pragma unroll
        for (int r = 0; r < 16; r++) sT[r] = EXP2(sT[r]);
        float s0 = sT[0] + sT[8],  s1 = sT[1] + sT[9];
        float s2 = sT[2] + sT[10], s3 = sT[3] + sT[11];
        float s4 = sT[4] + sT[12], s5 = sT[5] + sT[13];
        float s6 = sT[6] + sT[14], s7 = sT[7] + sT[15];
        s0 += s4; s1 += s5; s2 += s6; s3 += s7;
        l_r += (s0 + s2) + (s1 + s3);

        // pack P to bf16 pairs; permlane32_swap builds the A-frags directly
        unsigned pk0 = cvtpk(sT[0],  sT[1]);
        unsigned pk1 = cvtpk(sT[2],  sT[3]);
        unsigned pk2 = cvtpk(sT[4],  sT[5]);
        unsigned pk3 = cvtpk(sT[6],  sT[7]);
        unsigned pk4 = cvtpk(sT[8],  sT[9]);
        unsigned pk5 = cvtpk(sT[10], sT[11]);
        unsigned pk6 = cvtpk(sT[12], sT[13]);
        unsigned pk7 = cvtpk(sT[14], sT[15]);
        pl32swap(pk0, pk2);
        pl32swap(pk1, pk3);
        pl32swap(pk4, pk6);
        pl32swap(pk5, pk7);
        union { unsigned u[4]; short8 s; } pa0, pa1;
        pa0.u[0] = pk0; pa0.u[1] = pk1; pa0.u[2] = pk2; pa0.u[3] = pk3;
        pa1.u[0] = pk4; pa1.u[1] = pk5; pa1.u[2] = pk6; pa1.u[3] = pk7;

        // PV: 4 independent MFMAs
        o0a = MFMA32(pa0.s, vf[0][0], o0a);
        o1a = MFMA32(pa0.s, vf[1][0], o1a);
        o0b = MFMA32(pa1.s, vf[0][1], o0b);
        o1b = MFMA32(pa1.s, vf[1][1], o1b);

#pragma unroll
        for (int kd = 0; kd < 4; kd++) kf_cur[kd] = kf_nxt[kd];
    }

    l_r += __shfl_xor(l_r, 32);          // combine row halves once per strip
    float inv = __builtin_amdgcn_rcpf(l_r);
#pragma unroll
    for (int r = 0; r < 16; r++) {
        int crow = (r & 3) + 8 * (r >> 2) + 4 * hi;
        float ib = bq(inv, crow);
        int q = qbase + crow;
        unsigned short* zp = Z + ((size_t)b * S_ + q) * D_ + h * HD_;
        zp[c]      = f2bf((o0a[r] + o0b[r]) * ib);
        zp[32 + c] = f2bf((o1a[r] + o1b[r]) * ib);
    }
}

// ---------------- causal flash attention: 2-wave blocks, paired strips ----------------
// grid: 2048 blocks x 128 threads. Wave0 = strip pr, wave1 = strip 63-pr run
// CONCURRENTLY (16 waves/CU resident vs 8 sequential before). Per-CU block mix
// stays balanced (round-robin dispatch: pr values spread 4 apart).
__global__ __launch_bounds__(128, 4) void k_attn(const unsigned short* __restrict__ QF,
                                                 const unsigned short* __restrict__ KF,
                                                 const unsigned short* __restrict__ VF,
                                                 unsigned short* __restrict__ Z) {
    const int i = blockIdx.x;
    const int bh = (i & 7) * 8 + ((i >> 3) & 7);   // 8 bh per XCD -> K/V in one L2
    const int pr = i >> 6;                          // 0..31
    const int tid = threadIdx.x;
    const int wave = tid >> 6, lane = tid & 63;
    const int c = lane & 31, hi = lane >> 5;
    const int strip = wave ? (63 - pr) : pr;
    const unsigned short* QFb = QF + (size_t)bh * 131072;
    const unsigned short* KFb = KF + (size_t)bh * 131072;
    const unsigned short* VFb = VF + (size_t)bh * 131072;
    do_strip(strip, bh, c, hi, QFb, KFb, VFb, Z);
}

extern "C" void kernel_launch(void* const* d_in, const int* in_sizes, int n_in,
                              void* d_out, int out_size, void* d_ws, size_t ws_size,
                              hipStream_t stream) {
    const float* x     = (const float*)d_in[0];
    const float* w_qkv = (const float*)d_in[1];
    const float* b_qkv = (const float*)d_in[2];
    const float* w_out = (const float*)d_in[3];
    const float* b_out = (const float*)d_in[4];
    float* out = (float*)d_out;

    char* ws = (char*)d_ws;
    unsigned short* xb    = (unsigned short*)(ws + 0);          // 16 MB (aliased as Z later)
    unsigned short* wqkvT = (unsigned short*)(ws + 16777216);   // 6 MB
    unsigned short* woutT = (unsigned short*)(ws + 23068672);   // 2 MB
    unsigned short* qb    = (unsigned short*)(ws + 25165824);   // 16 MB (fragment-major Q)
    unsigned short* kb    = (unsigned short*)(ws + 41943040);   // 16 MB (fragment-major K)
    unsigned short* vtb   = (unsigned short*)(ws + 58720256);   // 16 MB (fragment-major V)
    unsigned short* zb    = xb;  // safe alias: xb consumed by QKV GEMM before attn writes zb

    k_cvt<<<8192, 256, 0, stream>>>(x, xb);
    k_transpose_cvt<<<dim3(96, 32), dim3(32, 8), 0, stream>>>(w_qkv, wqkvT, 1024, 3072);
    k_transpose_cvt<<<dim3(32, 32), dim3(32, 8), 0, stream>>>(w_out, woutT, 1024, 1024);
    k_gemm8<1><<<dim3(16, 32), 512, 0, stream>>>(xb, wqkvT, b_qkv, qb, kb, vtb,
                                                 8192, 3072, 1024, 0);
    k_gemm8<0><<<dim3(8, 32), 512, 0, stream>>>(xb, wqkvT, b_qkv, qb, kb, vtb,
                                                8192, 3072, 1024, 2048);
    k_attn<<<2048, 128, 0, stream>>>(qb, kb, vtb, zb);
    k_gemm_out8<<<dim3(8, 32), 512, 0, stream>>>(zb, woutT, b_out, out, 8192, 1024, 1024);
}

// Round 21
// 169.370 us; speedup vs baseline: 1.8173x; 1.8173x over previous
//
#include <hip/hip_runtime.h>
#include <hip/hip_bf16.h>
#include <stdint.h>

#define B_   4
#define S_   2048
#define H_   16
#define HD_  64
#define D_   1024

typedef short  short8  __attribute__((ext_vector_type(8)));
typedef float  f32x4   __attribute__((ext_vector_type(4)));
typedef float  f32x16  __attribute__((ext_vector_type(16)));

__device__ __forceinline__ unsigned short f2bf(float f) {
    union { float f; unsigned u; } v; v.f = f;
    unsigned r = v.u + 0x7fffu + ((v.u >> 16) & 1u);
    return (unsigned short)(r >> 16);
}

#if __has_builtin(__builtin_amdgcn_exp2f)
#define EXP2(x) __builtin_amdgcn_exp2f(x)
#else
#define EXP2(x) exp2f(x)
#endif

__device__ __forceinline__ unsigned cvtpk(float lo, float hi) {
    unsigned r;
    asm("v_cvt_pk_bf16_f32 %0, %1, %2" : "=v"(r) : "v"(lo), "v"(hi));
    return r;
}

__device__ __forceinline__ float bq(float v, int srclane) {
    return __int_as_float(__builtin_amdgcn_ds_bpermute(srclane << 2, __float_as_int(v)));
}

// v_permlane32_swap_b32: x' = [x.lo | y.lo], y' = [x.hi | y.hi]
__device__ __forceinline__ void pl32swap(unsigned &x, unsigned &y) {
    asm volatile("v_permlane32_swap_b32 %0, %1" : "+v"(x), "+v"(y));
}

#define MFMA32(a, b, c) __builtin_amdgcn_mfma_f32_32x32x16_bf16(a, b, c, 0, 0, 0)
#define MFMA16(a, b, c) __builtin_amdgcn_mfma_f32_16x16x32_bf16(a, b, c, 0, 0, 0)

// ---------------- fp32 -> bf16 convert (vectorized) ----------------
__global__ __launch_bounds__(256) void k_cvt(const float* __restrict__ in,
                                             unsigned short* __restrict__ out) {
    int i = (blockIdx.x * 256 + threadIdx.x) * 4;
    float4 f = *(const float4*)(in + i);
    ushort4 o;
    o.x = f2bf(f.x); o.y = f2bf(f.y); o.z = f2bf(f.z); o.w = f2bf(f.w);
    *(ushort4*)(out + i) = o;
}

// ---------- transpose + convert: in[K][N] f32 -> out[N][K] bf16 ----------
__global__ __launch_bounds__(256) void k_transpose_cvt(const float* __restrict__ in,
                                                       unsigned short* __restrict__ out,
                                                       int K, int N) {
    __shared__ float tile[32][33];
    int n0 = blockIdx.x * 32, k0 = blockIdx.y * 32;
    int tx = threadIdx.x, ty = threadIdx.y;
#pragma unroll
    for (int i = 0; i < 32; i += 8)
        tile[ty + i][tx] = in[(size_t)(k0 + ty + i) * N + n0 + tx];
    __syncthreads();
#pragma unroll
    for (int i = 0; i < 32; i += 8)
        out[(size_t)(n0 + ty + i) * K + k0 + tx] = f2bf(tile[tx][ty + i]);
}

__device__ __forceinline__ void async_load16(const unsigned short* g, unsigned short* l) {
    __builtin_amdgcn_global_load_lds(
        (const __attribute__((address_space(1))) unsigned int*)g,
        (__attribute__((address_space(3))) unsigned int*)l, 16, 0, 0);
}

// ============ balanced 8-wave 256x128 GEMM (QKV projection) ============
// (r19-proven, unchanged) Triple-buffered LDS, 2 phases/K-tile, vmcnt(6).
template <int TPOSED>
__global__ __launch_bounds__(512, 1) void k_gemm8(const unsigned short* __restrict__ A,
                                                  const unsigned short* __restrict__ BT,
                                                  const float* __restrict__ bias,
                                                  unsigned short* __restrict__ qb,
                                                  unsigned short* __restrict__ kb,
                                                  unsigned short* __restrict__ vtb,
                                                  int M, int N, int K, int nbase) {
    __shared__ __attribute__((aligned(16))) unsigned short A0s[256 * 64];
    __shared__ __attribute__((aligned(16))) unsigned short A1s[256 * 64];
    __shared__ __attribute__((aligned(16))) unsigned short A2s[256 * 64];
    __shared__ __attribute__((aligned(16))) unsigned short W0s[128 * 64];
    __shared__ __attribute__((aligned(16))) unsigned short W1s[128 * 64];
    __shared__ __attribute__((aligned(16))) unsigned short W2s[128 * 64];
    const int tid = threadIdx.x, wave = tid >> 6, lane = tid & 63;
    const int wR = wave >> 2, wC = wave & 3;
    const int m0 = blockIdx.y * 256, n0 = nbase + blockIdx.x * 128;

    const unsigned short* AG = A + (size_t)m0 * K;
    const unsigned short* WG = BT + (size_t)n0 * K;

    const int rbase = wave * 8 + (lane >> 3);
    const int scol8 = ((lane & 7) ^ ((lane >> 3) & 7)) * 8;
    const int sdst  = wave * 512;
    const int q15 = lane & 15, q4 = (lane >> 4) << 2;
    const int cb0 = ((lane >> 4) * 16) ^ ((lane & 7) << 4);
    const int cb1 = (64 + (lane >> 4) * 16) ^ ((lane & 7) << 4);

    f32x4 acc[2][4][2] = {};

#define STAGE3(SA, SW, KT, KH)                                                        \
    if ((KH) == 0) {                                                                  \
        async_load16(AG + (size_t)(rbase)       * K + (KT) + scol8, (SA) + 0 * 4096 + sdst); \
        async_load16(AG + (size_t)(64 + rbase)  * K + (KT) + scol8, (SA) + 1 * 4096 + sdst); \
        async_load16(WG + (size_t)(rbase)       * K + (KT) + scol8, (SW) + 0 * 4096 + sdst); \
    } else {                                                                          \
        async_load16(AG + (size_t)(128 + rbase) * K + (KT) + scol8, (SA) + 2 * 4096 + sdst); \
        async_load16(AG + (size_t)(192 + rbase) * K + (KT) + scol8, (SA) + 3 * 4096 + sdst); \
        async_load16(WG + (size_t)(64 + rbase)  * K + (KT) + scol8, (SW) + 1 * 4096 + sdst); \
    }

#define PHASEBODY(CA, CW, SA, SW, MORE, KT2, KH, CB)                                  \
    {                                                                                 \
        short8 xf[2][4], yf[2][2];                                                    \
        if (TPOSED) {                                                                 \
            _Pragma("unroll")                                                         \
            for (int i = 0; i < 4; ++i)                                               \
                xf[0][i] = *(const short8*)((const char*)(CW) + (wR * 64 + i * 16 + q15) * 128 + (CB)); \
            _Pragma("unroll")                                                         \
            for (int h = 0; h < 2; ++h)                                               \
                _Pragma("unroll")                                                     \
                for (int j = 0; j < 2; ++j)                                           \
                    yf[h][j] = *(const short8*)((const char*)(CA) + (h * 128 + wC * 32 + j * 16 + q15) * 128 + (CB)); \
        } else {                                                                      \
            _Pragma("unroll")                                                         \
            for (int h = 0; h < 2; ++h)                                               \
                _Pragma("unroll")                                                     \
                for (int i = 0; i < 4; ++i)                                           \
                    xf[h][i] = *(const short8*)((const char*)(CA) + (h * 128 + wR * 64 + i * 16 + q15) * 128 + (CB)); \
            _Pragma("unroll")                                                         \
            for (int j = 0; j < 2; ++j)                                               \
                yf[0][j] = *(const short8*)((const char*)(CW) + (wC * 32 + j * 16 + q15) * 128 + (CB)); \
        }                                                                             \
        if (MORE) {                                                                   \
            STAGE3(SA, SW, KT2, KH)                                                   \
            asm volatile("s_waitcnt vmcnt(6)" ::: "memory");                          \
        } else {                                                                      \
            asm volatile("s_waitcnt vmcnt(0)" ::: "memory");                          \
        }                                                                             \
        __builtin_amdgcn_s_barrier();                                                 \
        asm volatile("s_waitcnt lgkmcnt(0)" ::: "memory");                            \
        __builtin_amdgcn_sched_barrier(0);                                            \
        __builtin_amdgcn_s_setprio(1);                                                \
        _Pragma("unroll")                                                             \
        for (int h = 0; h < 2; ++h)                                                   \
            _Pragma("unroll")                                                         \
            for (int i = 0; i < 4; ++i)                                               \
                _Pragma("unroll")                                                     \
                for (int j = 0; j < 2; ++j)                                           \
                    acc[h][i][j] = MFMA16(TPOSED ? xf[0][i] : xf[h][i],               \
                                          TPOSED ? yf[h][j] : yf[0][j],               \
                                          acc[h][i][j]);                              \
        __builtin_amdgcn_s_setprio(0);                                                \
        asm volatile("" ::: "memory");                                                \
        __builtin_amdgcn_s_barrier();                                                 \
    }

#define TILEBODY(CA, CW, SA, SW, TC)                                                  \
    {                                                                                 \
        const int more_ = ((TC) + 2) < 16;                                            \
        const int kt2_ = ((TC) + 2) * 64;                                             \
        PHASEBODY(CA, CW, SA, SW, more_, kt2_, 0, cb0)                                \
        PHASEBODY(CA, CW, SA, SW, more_, kt2_, 1, cb1)                                \
    }

    STAGE3(A0s, W0s, 0, 0)
    STAGE3(A0s, W0s, 0, 1)
    STAGE3(A1s, W1s, 64, 0)
    STAGE3(A1s, W1s, 64, 1)
    asm volatile("s_waitcnt vmcnt(6)" ::: "memory");
    __builtin_amdgcn_s_barrier();

    for (int t = 0; t < 15; t += 3) {
        TILEBODY(A0s, W0s, A2s, W2s, t)
        TILEBODY(A1s, W1s, A0s, W0s, t + 1)
        TILEBODY(A2s, W2s, A1s, W1s, t + 2)
    }
    TILEBODY(A0s, W0s, A2s, W2s, 15)
#undef STAGE3
#undef PHASEBODY
#undef TILEBODY

    if (TPOSED) {
        unsigned short* dst = (n0 < 1024) ? qb : kb;
        const float scale = (n0 < 1024) ? 0.18033688011112042f : 1.0f;
#pragma unroll
        for (int i = 0; i < 4; ++i) {
            int nr = n0 + wR * 64 + i * 16 + q4;
            float4 bv4 = *(const float4*)(bias + nr);
            int d0 = nr & 63, hh = (nr & 1023) >> 6;
#pragma unroll
            for (int h = 0; h < 2; ++h)
#pragma unroll
            for (int j = 0; j < 2; ++j) {
                int mc = m0 + h * 128 + wC * 32 + j * 16 + q15;
                int b = mc >> 11, s = mc & 2047;
                size_t bh = (size_t)(b * 16 + hh);
                f32x4 a = acc[h][i][j];
                ushort4 o;
                o.x = f2bf((a[0] + bv4.x) * scale);
                o.y = f2bf((a[1] + bv4.y) * scale);
                o.z = f2bf((a[2] + bv4.z) * scale);
                o.w = f2bf((a[3] + bv4.w) * scale);
                size_t off = bh * 131072 +
                    (size_t)((s >> 5) * 4 + (d0 >> 4)) * 512 +
                    ((s & 31) * 2 + ((d0 >> 3) & 1)) * 8 + (d0 & 7);
                *(ushort4*)(dst + off) = o;
            }
        }
    } else {
#pragma unroll
        for (int h = 0; h < 2; ++h)
#pragma unroll
        for (int i = 0; i < 4; ++i) {
            int mr = m0 + h * 128 + wR * 64 + i * 16 + q4;
            int b = mr >> 11, s0 = mr & 2047;
#pragma unroll
            for (int j = 0; j < 2; ++j) {
                int nc = n0 + wC * 32 + j * 16 + q15;
                int rem = nc & 1023, hh = rem >> 6, d = rem & 63;
                float bv = bias[nc];
                f32x4 a = acc[h][i][j];
                ushort4 o;
                o.x = f2bf(a[0] + bv);
                o.y = f2bf(a[1] + bv);
                o.z = f2bf(a[2] + bv);
                o.w = f2bf(a[3] + bv);
                size_t bh = (size_t)(b * 16 + hh);
                size_t off = bh * 131072 +
                    (size_t)((s0 >> 5) * 4 + (d >> 5) * 2 + ((s0 >> 4) & 1)) * 512 +
                    (((d & 31) << 1) + ((s0 >> 3) & 1)) * 8 + (s0 & 7);
                *(ushort4*)(vtb + off) = o;
            }
        }
    }
}

// ============ output projection: 8-phase 256x128, fp32 float4 epilogue ============
// (r20-verified) grid 8x32 = 256 blocks = exactly 1/CU.
__global__ __launch_bounds__(512, 1) void k_gemm_out8(const unsigned short* __restrict__ A,
                                                      const unsigned short* __restrict__ BT,
                                                      const float* __restrict__ bias,
                                                      float* __restrict__ outf,
                                                      int M, int N, int K) {
    __shared__ __attribute__((aligned(16))) unsigned short A0s[256 * 64];
    __shared__ __attribute__((aligned(16))) unsigned short A1s[256 * 64];
    __shared__ __attribute__((aligned(16))) unsigned short A2s[256 * 64];
    __shared__ __attribute__((aligned(16))) unsigned short W0s[128 * 64];
    __shared__ __attribute__((aligned(16))) unsigned short W1s[128 * 64];
    __shared__ __attribute__((aligned(16))) unsigned short W2s[128 * 64];
    const int tid = threadIdx.x, wave = tid >> 6, lane = tid & 63;
    const int wR = wave >> 2, wC = wave & 3;
    const int m0 = blockIdx.y * 256, n0 = blockIdx.x * 128;

    const unsigned short* AG = A + (size_t)m0 * K;
    const unsigned short* WG = BT + (size_t)n0 * K;

    const int rbase = wave * 8 + (lane >> 3);
    const int scol8 = ((lane & 7) ^ ((lane >> 3) & 7)) * 8;
    const int sdst  = wave * 512;
    const int q15 = lane & 15, q4 = (lane >> 4) << 2;
    const int cb0 = ((lane >> 4) * 16) ^ ((lane & 7) << 4);
    const int cb1 = (64 + (lane >> 4) * 16) ^ ((lane & 7) << 4);

    f32x4 acc[2][4][2] = {};

#define STAGE3O(SA, SW, KT, KH)                                                       \
    if ((KH) == 0) {                                                                  \
        async_load16(AG + (size_t)(rbase)       * K + (KT) + scol8, (SA) + 0 * 4096 + sdst); \
        async_load16(AG + (size_t)(64 + rbase)  * K + (KT) + scol8, (SA) + 1 * 4096 + sdst); \
        async_load16(WG + (size_t)(rbase)       * K + (KT) + scol8, (SW) + 0 * 4096 + sdst); \
    } else {                                                                          \
        async_load16(AG + (size_t)(128 + rbase) * K + (KT) + scol8, (SA) + 2 * 4096 + sdst); \
        async_load16(AG + (size_t)(192 + rbase) * K + (KT) + scol8, (SA) + 3 * 4096 + sdst); \
        async_load16(WG + (size_t)(64 + rbase)  * K + (KT) + scol8, (SW) + 1 * 4096 + sdst); \
    }

#define PHASEBODYO(CA, CW, SA, SW, MORE, KT2, KH, CB)                                 \
    {                                                                                 \
        short8 xf[4], yf[2][2];                                                       \
        _Pragma("unroll")                                                             \
        for (int i = 0; i < 4; ++i)                                                   \
            xf[i] = *(const short8*)((const char*)(CW) + (wR * 64 + i * 16 + q15) * 128 + (CB)); \
        _Pragma("unroll")                                                             \
        for (int h = 0; h < 2; ++h)                                                   \
            _Pragma("unroll")                                                         \
            for (int j = 0; j < 2; ++j)                                               \
                yf[h][j] = *(const short8*)((const char*)(CA) + (h * 128 + wC * 32 + j * 16 + q15) * 128 + (CB)); \
        if (MORE) {                                                                   \
            STAGE3O(SA, SW, KT2, KH)                                                  \
            asm volatile("s_waitcnt vmcnt(6)" ::: "memory");                          \
        } else {                                                                      \
            asm volatile("s_waitcnt vmcnt(0)" ::: "memory");                          \
        }                                                                             \
        __builtin_amdgcn_s_barrier();                                                 \
        asm volatile("s_waitcnt lgkmcnt(0)" ::: "memory");                            \
        __builtin_amdgcn_sched_barrier(0);                                            \
        __builtin_amdgcn_s_setprio(1);                                                \
        _Pragma("unroll")                                                             \
        for (int h = 0; h < 2; ++h)                                                   \
            _Pragma("unroll")                                                         \
            for (int i = 0; i < 4; ++i)                                               \
                _Pragma("unroll")                                                     \
                for (int j = 0; j < 2; ++j)                                           \
                    acc[h][i][j] = MFMA16(xf[i], yf[h][j], acc[h][i][j]);             \
        __builtin_amdgcn_s_setprio(0);                                                \
        asm volatile("" ::: "memory");                                                \
        __builtin_amdgcn_s_barrier();                                                 \
    }

#define TILEBODYO(CA, CW, SA, SW, TC)                                                 \
    {                                                                                 \
        const int more_ = ((TC) + 2) < 16;                                            \
        const int kt2_ = ((TC) + 2) * 64;                                             \
        PHASEBODYO(CA, CW, SA, SW, more_, kt2_, 0, cb0)                               \
        PHASEBODYO(CA, CW, SA, SW, more_, kt2_, 1, cb1)                               \
    }

    STAGE3O(A0s, W0s, 0, 0)
    STAGE3O(A0s, W0s, 0, 1)
    STAGE3O(A1s, W1s, 64, 0)
    STAGE3O(A1s, W1s, 64, 1)
    asm volatile("s_waitcnt vmcnt(6)" ::: "memory");
    __builtin_amdgcn_s_barrier();

    for (int t = 0; t < 15; t += 3) {
        TILEBODYO(A0s, W0s, A2s, W2s, t)
        TILEBODYO(A1s, W1s, A0s, W0s, t + 1)
        TILEBODYO(A2s, W2s, A1s, W1s, t + 2)
    }
    TILEBODYO(A0s, W0s, A2s, W2s, 15)
#undef STAGE3O
#undef PHASEBODYO
#undef TILEBODYO

#pragma unroll
    for (int i = 0; i < 4; ++i) {
        int nr = n0 + wR * 64 + i * 16 + q4;
        float4 bv4 = *(const float4*)(bias + nr);
#pragma unroll
        for (int h = 0; h < 2; ++h)
#pragma unroll
        for (int j = 0; j < 2; ++j) {
            int mc = m0 + h * 128 + wC * 32 + j * 16 + q15;
            f32x4 a = acc[h][i][j];
            float4 o;
            o.x = a[0] + bv4.x;
            o.y = a[1] + bv4.y;
            o.z = a[2] + bv4.z;
            o.w = a[3] + bv4.w;
            *(float4*)(outf + (size_t)mc * N + nr) = o;
        }
    }
}

// ---- one 32-q strip: fixed-max softmax, split MFMA accumulators, permlane pack.
// All Q/K/V fragment loads are 1KB coalesced wave-loads from fragment-major buffers. ----
__device__ __forceinline__ void do_strip(int strip, int bh, int c, int hi,
                                         const unsigned short* __restrict__ QFb,
                                         const unsigned short* __restrict__ KFb,
                                         const unsigned short* __restrict__ VFb,
                                         unsigned short* __restrict__ Z) {
    const int qbase = strip * 32;
    const int b = bh >> 4, h = bh & 15;
    const int lp8 = ((c << 1) + hi) << 3;      // lane-slot offset within 512-elem block

    short8 qf[4];
#pragma unroll
    for (int kd = 0; kd < 4; kd++)
        qf[kd] = *(const short8*)(QFb + (strip * 4 + kd) * 512 + lp8);

    f32x16 o0a = {}, o0b = {}, o1a = {}, o1b = {};
    float l_r = 0.f;
    const int nkv = strip + 1;

    short8 kf_cur[4], kf_nxt[4];
#pragma unroll
    for (int kd = 0; kd < 4; kd++)
        kf_cur[kd] = *(const short8*)(KFb + kd * 512 + lp8);

    for (int tt = 0; tt < nkv; ++tt) {
        const int tn = (tt + 1 < nkv) ? (tt + 1) : tt;    // clamped prefetch
#pragma unroll
        for (int kd = 0; kd < 4; kd++)
            kf_nxt[kd] = *(const short8*)(KFb + (tn * 4 + kd) * 512 + lp8);

        short8 vf[2][2];
#pragma unroll
        for (int dt = 0; dt < 2; dt++)
#pragma unroll
            for (int ks = 0; ks < 2; ks++)
                vf[dt][ks] = *(const short8*)(VFb + (tt * 4 + dt * 2 + ks) * 512 + lp8);

        // QK^T: two independent 2-chains
        f32x16 sTa = {}, sTb = {};
        sTa = MFMA32(kf_cur[0], qf[0], sTa);
        sTb = MFMA32(kf_cur[2], qf[2], sTb);
        sTa = MFMA32(kf_cur[1], qf[1], sTa);
        sTb = MFMA32(kf_cur[3], qf[3], sTb);
        f32x16 sT;
#pragma unroll
        for (int r = 0; r < 16; r++) sT[r] = sTa[r] + sTb[r];

        if (tt * 32 == qbase) {          // diagonal tile: mask t_local > q_local
#pragma unroll
            for (int r = 0; r < 16; r++) {
                int tl = (r & 3) + 8 * (r >> 2) + 4 * hi;
                if (tl > c) sT[r] = -1e30f;
            }
        }

        // fixed-max softmax: P = exp2(s) directly (logits bounded, f32-safe)
#pragma unroll
        for (int r = 0; r < 16; r++) sT[r] = EXP2(sT[r]);
        float s0 = sT[0] + sT[8],  s1 = sT[1] + sT[9];
        float s2 = sT[2] + sT[10], s3 = sT[3] + sT[11];
        float s4 = sT[4] + sT[12], s5 = sT[5] + sT[13];
        float s6 = sT[6] + sT[14], s7 = sT[7] + sT[15];
        s0 += s4; s1 += s5; s2 += s6; s3 += s7;
        l_r += (s0 + s2) + (s1 + s3);

        // pack P to bf16 pairs; permlane32_swap builds the A-frags directly
        unsigned pk0 = cvtpk(sT[0],  sT[1]);
        unsigned pk1 = cvtpk(sT[2],  sT[3]);
        unsigned pk2 = cvtpk(sT[4],  sT[5]);
        unsigned pk3 = cvtpk(sT[6],  sT[7]);
        unsigned pk4 = cvtpk(sT[8],  sT[9]);
        unsigned pk5 = cvtpk(sT[10], sT[11]);
        unsigned pk6 = cvtpk(sT[12], sT[13]);
        unsigned pk7 = cvtpk(sT[14], sT[15]);
        pl32swap(pk0, pk2);
        pl32swap(pk1, pk3);
        pl32swap(pk4, pk6);
        pl32swap(pk5, pk7);
        union { unsigned u[4]; short8 s; } pa0, pa1;
        pa0.u[0] = pk0; pa0.u[1] = pk1; pa0.u[2] = pk2; pa0.u[3] = pk3;
        pa1.u[0] = pk4; pa1.u[1] = pk5; pa1.u[2] = pk6; pa1.u[3] = pk7;

        // PV: 4 independent MFMAs
        o0a = MFMA32(pa0.s, vf[0][0], o0a);
        o1a = MFMA32(pa0.s, vf[1][0], o1a);
        o0b = MFMA32(pa1.s, vf[0][1], o0b);
        o1b = MFMA32(pa1.s, vf[1][1], o1b);

#pragma unroll
        for (int kd = 0; kd < 4; kd++) kf_cur[kd] = kf_nxt[kd];
    }

    l_r += __shfl_xor(l_r, 32);          // combine row halves once per strip
    float inv = __builtin_amdgcn_rcpf(l_r);
#pragma unroll
    for (int r = 0; r < 16; r++) {
        int crow = (r & 3) + 8 * (r >> 2) + 4 * hi;
        float ib = bq(inv, crow);
        int q = qbase + crow;
        unsigned short* zp = Z + ((size_t)b * S_ + q) * D_ + h * HD_;
        zp[c]      = f2bf((o0a[r] + o0b[r]) * ib);
        zp[32 + c] = f2bf((o1a[r] + o1b[r]) * ib);
    }
}

// ---------------- causal flash attention: 2-wave blocks, paired strips ----------------
// grid: 2048 blocks x 128 threads. Wave0 = strip pr, wave1 = strip 63-pr run
// CONCURRENTLY. launch_bounds min-waves = 2 (NOT 4): do_strip needs ~80 VGPR;
// capping at 64 (r20) spilled the f32x16 accumulators to scratch (363MB writes).
__global__ __launch_bounds__(128, 2) void k_attn(const unsigned short* __restrict__ QF,
                                                 const unsigned short* __restrict__ KF,
                                                 const unsigned short* __restrict__ VF,
                                                 unsigned short* __restrict__ Z) {
    const int i = blockIdx.x;
    const int bh = (i & 7) * 8 + ((i >> 3) & 7);   // 8 bh per XCD -> K/V in one L2
    const int pr = i >> 6;                          // 0..31
    const int tid = threadIdx.x;
    const int wave = tid >> 6, lane = tid & 63;
    const int c = lane & 31, hi = lane >> 5;
    const int strip = wave ? (63 - pr) : pr;
    const unsigned short* QFb = QF + (size_t)bh * 131072;
    const unsigned short* KFb = KF + (size_t)bh * 131072;
    const unsigned short* VFb = VF + (size_t)bh * 131072;
    do_strip(strip, bh, c, hi, QFb, KFb, VFb, Z);
}

extern "C" void kernel_launch(void* const* d_in, const int* in_sizes, int n_in,
                              void* d_out, int out_size, void* d_ws, size_t ws_size,
                              hipStream_t stream) {
    const float* x     = (const float*)d_in[0];
    const float* w_qkv = (const float*)d_in[1];
    const float* b_qkv = (const float*)d_in[2];
    const float* w_out = (const float*)d_in[3];
    const float* b_out = (const float*)d_in[4];
    float* out = (float*)d_out;

    char* ws = (char*)d_ws;
    unsigned short* xb    = (unsigned short*)(ws + 0);          // 16 MB (aliased as Z later)
    unsigned short* wqkvT = (unsigned short*)(ws + 16777216);   // 6 MB
    unsigned short* woutT = (unsigned short*)(ws + 23068672);   // 2 MB
    unsigned short* qb    = (unsigned short*)(ws + 25165824);   // 16 MB (fragment-major Q)
    unsigned short* kb    = (unsigned short*)(ws + 41943040);   // 16 MB (fragment-major K)
    unsigned short* vtb   = (unsigned short*)(ws + 58720256);   // 16 MB (fragment-major V)
    unsigned short* zb    = xb;  // safe alias: xb consumed by QKV GEMM before attn writes zb

    k_cvt<<<8192, 256, 0, stream>>>(x, xb);
    k_transpose_cvt<<<dim3(96, 32), dim3(32, 8), 0, stream>>>(w_qkv, wqkvT, 1024, 3072);
    k_transpose_cvt<<<dim3(32, 32), dim3(32, 8), 0, stream>>>(w_out, woutT, 1024, 1024);
    k_gemm8<1><<<dim3(16, 32), 512, 0, stream>>>(xb, wqkvT, b_qkv, qb, kb, vtb,
                                                 8192, 3072, 1024, 0);
    k_gemm8<0><<<dim3(8, 32), 512, 0, stream>>>(xb, wqkvT, b_qkv, qb, kb, vtb,
                                                8192, 3072, 1024, 2048);
    k_attn<<<2048, 128, 0, stream>>>(qb, kb, vtb, zb);
    k_gemm_out8<<<dim3(8, 32), 512, 0, stream>>>(zb, woutT, b_out, out, 8192, 1024, 1024);
}